// Round 2
// baseline (141726.099 us; speedup 1.0000x reference)
//
#include <hip/hip_runtime.h>
#include <cstdint>

typedef unsigned long long ull;
#define SCOPE __HIP_MEMORY_SCOPE_AGENT

__device__ __forceinline__ ull ald(const ull* p) {
  return __hip_atomic_load(p, __ATOMIC_RELAXED, SCOPE);
}
__device__ __forceinline__ void ast(ull* p, ull v) {
  __hip_atomic_store(p, v, __ATOMIC_RELAXED, SCOPE);
}
__device__ __forceinline__ float vlo(ull v) { return __uint_as_float((unsigned)v); }
__device__ __forceinline__ unsigned thi(ull v) { return (unsigned)(v >> 32); }
__device__ __forceinline__ ull pack(float f, unsigned t) {
  return ((ull)t << 32) | (ull)__float_as_uint(f);
}
__device__ __forceinline__ float sigm(float x) { return 1.f / (1.f + __expf(-x)); }
__device__ __forceinline__ float tanh_(float x) { return 1.f - 2.f / (__expf(2.f * x) + 1.f); }

// ws layout in 8-byte (value,tag) pairs:
// Y0 ring: 4 slots x 512 @ 0      (h0 == y0 of layer0)
// Y1 ring: 4 slots x 512 @ 2048
// H1 ring: 4 slots x 512 @ 4096
// X  ring: 4 slots x 256 @ 6144   (fed-back model input)
#define Y0 0
#define Y1 2048
#define H1 4096
#define XR 6144

// Tag protocol (cell index u is global over all 3*len*128 cells):
//  y0[u] elements carry tag u+1 in slot u&3.   L0 cell u polls h0[u-1]: tag u  (slot (u+3)&3)
//  y1/h1[u] carry tag u+1 in slot u&3.         L1 cell u polls y0[u]: tag u+1; h1[u-1]: tag u
//  x[u] carries tag u+1 in slot u&3 (init: slots 0..2 = embeddings, tags 1..3;
//  out cell v writes x[v+3] = tag v+4).        L0 cell u polls x[u]: tag u+1
// Ring-overwrite safety (depth 4) follows transitively: a wave's __all over its
// full input vector implies every producer wave of the (u-3)-lagged stage finished,
// which implies all readers of the slot being overwritten are done. (Exact-match
// tags mean a violated ring would hang, not silently corrupt.)

__global__ void mg_init(ull* __restrict__ ws8, const float* __restrict__ emb,
                        const int* __restrict__ tempo, const int* __restrict__ keysig,
                        const int* __restrict__ lenp) {
  const int tid = blockIdx.x * blockDim.x + threadIdx.x;
  const int n = gridDim.x * blockDim.x;
  for (int i = tid; i < 6144; i += n) ast(ws8 + i, 0ull);
  for (int i = tid; i < 1024; i += n) {
    const int s = i >> 8, j = i & 255;
    ull v = 0ull;
    if (s < 3) {
      const int r = (s == 0) ? tempo[0] : ((s == 1) ? keysig[0] : lenp[0]);
      v = pack(emb[r * 256 + j], (unsigned)(s + 1));
    }
    ast(ws8 + XR + i, v);
  }
}

// Blocks [0,32): layer0.  [32,64): layer1.  [64,72): output projection.
// No __syncthreads / LDS / counters anywhere in the steady loop: waves are
// fully self-timed via tagged 8B atomics at agent scope (sc1, LLC coherent).
__global__ __launch_bounds__(512, 2) void mg_main(
    ull* __restrict__ ws8,
    const float* __restrict__ Wih0, const float* __restrict__ Whh0,
    const float* __restrict__ bih0, const float* __restrict__ bhh0,
    const float* __restrict__ Wih1, const float* __restrict__ Whh1,
    const float* __restrict__ bih1, const float* __restrict__ bhh1,
    const float* __restrict__ Wp, const float* __restrict__ bp,
    const float* __restrict__ Wv, const float* __restrict__ bv,
    const int* __restrict__ lenp, float* __restrict__ dout) {
  const int bid = blockIdx.x;
  const int tid = threadIdx.x;
  const int wv = tid >> 6;  // wave 0..7
  const int l = tid & 63;   // lane
  const int NT = 3 * lenp[0] * 128;
  ull* y0r = ws8 + Y0;
  ull* y1r = ws8 + Y1;
  ull* h1r = ws8 + H1;
  ull* xr = ws8 + XR;

  if (bid < 32) {
    // ================= layer 0 =================
    // wave owns h0[k], k = 16*bid + 2*wv + {0,1}; 8 gate rows x 12 col-chunks.
    const int beta = bid;
    float w[96], base[8];
    float cst0 = 0.f, cst1 = 0.f;
#pragma unroll
    for (int r = 0; r < 8; ++r) {
      const int row = ((r & 3) << 9) + (beta << 4) + (wv << 1) + (r >> 2);
      base[r] = bih0[row] + bhh0[row];
#pragma unroll
      for (int j = 0; j < 12; ++j) {
        const int c = l + (j << 6);
        w[r * 12 + j] = (j < 8) ? Whh0[row * 512 + c] : Wih0[(row << 8) + (c - 512)];
      }
    }
    const int kg = (beta << 4) + (wv << 1);
    for (int u = 0; u < NT; ++u) {
      const ull* hp = y0r + (((u + 3) & 3) << 9);
      const ull* xp = xr + ((u & 3) << 8);
      const unsigned th = (unsigned)u, tx = (unsigned)(u + 1);
      ull d[12];
      while (true) {
        bool ok = true;
#pragma unroll
        for (int j = 0; j < 8; ++j) { d[j] = ald(hp + (j << 6) + l); ok &= (thi(d[j]) == th); }
#pragma unroll
        for (int j = 0; j < 4; ++j) { d[8 + j] = ald(xp + (j << 6) + l); ok &= (thi(d[8 + j]) == tx); }
        if (__all(ok)) break;
      }
      float acc[8] = {0.f, 0.f, 0.f, 0.f, 0.f, 0.f, 0.f, 0.f};
#pragma unroll
      for (int j = 0; j < 12; ++j) {
        const float hv = vlo(d[j]);
#pragma unroll
        for (int r = 0; r < 8; ++r) acc[r] = fmaf(w[r * 12 + j], hv, acc[r]);
      }
#pragma unroll
      for (int r = 0; r < 8; ++r) {
        float s = acc[r];
#pragma unroll
        for (int off = 32; off > 0; off >>= 1) s += __shfl_xor(s, off, 64);
        acc[r] = s + base[r];
      }
      float hn0, hn1;
      {
        const float cn = sigm(acc[1]) * cst0 + sigm(acc[0]) * tanh_(acc[2]);
        cst0 = cn;
        hn0 = sigm(acc[3]) * tanh_(cn);
      }
      {
        const float cn = sigm(acc[5]) * cst1 + sigm(acc[4]) * tanh_(acc[6]);
        cst1 = cn;
        hn1 = sigm(acc[7]) * tanh_(cn);
      }
      if (l < 2) ast(y0r + ((u & 3) << 9) + kg + l, pack(l ? hn1 : hn0, (unsigned)(u + 1)));
    }
  } else if (bid < 64) {
    // ================= layer 1 =================
    const int beta = bid - 32;
    float w[128], base[8];
    float cst0 = 0.f, cst1 = 0.f;
#pragma unroll
    for (int r = 0; r < 8; ++r) {
      const int row = ((r & 3) << 9) + (beta << 4) + (wv << 1) + (r >> 2);
      base[r] = bih1[row] + bhh1[row];
#pragma unroll
      for (int j = 0; j < 16; ++j) {
        const int c = l + (j << 6);
        w[r * 16 + j] = (j < 8) ? Wih1[row * 512 + c] : Whh1[row * 512 + (c - 512)];
      }
    }
    const int kg = (beta << 4) + (wv << 1);
    for (int u = 0; u < NT; ++u) {
      const ull* yp = y0r + ((u & 3) << 9);
      const ull* hp = h1r + (((u + 3) & 3) << 9);
      const unsigned ty = (unsigned)(u + 1), th = (unsigned)u;
      ull d[16];
      while (true) {
        bool ok = true;
#pragma unroll
        for (int j = 0; j < 8; ++j) { d[j] = ald(yp + (j << 6) + l); ok &= (thi(d[j]) == ty); }
#pragma unroll
        for (int j = 0; j < 8; ++j) { d[8 + j] = ald(hp + (j << 6) + l); ok &= (thi(d[8 + j]) == th); }
        if (__all(ok)) break;
      }
      float acc[8] = {0.f, 0.f, 0.f, 0.f, 0.f, 0.f, 0.f, 0.f};
#pragma unroll
      for (int j = 0; j < 16; ++j) {
        const float hv = vlo(d[j]);
#pragma unroll
        for (int r = 0; r < 8; ++r) acc[r] = fmaf(w[r * 16 + j], hv, acc[r]);
      }
#pragma unroll
      for (int r = 0; r < 8; ++r) {
        float s = acc[r];
#pragma unroll
        for (int off = 32; off > 0; off >>= 1) s += __shfl_xor(s, off, 64);
        acc[r] = s + base[r];
      }
      float hn0, hn1;
      {
        const float cn = sigm(acc[1]) * cst0 + sigm(acc[0]) * tanh_(acc[2]);
        cst0 = cn;
        hn0 = sigm(acc[3]) * tanh_(cn);
      }
      {
        const float cn = sigm(acc[5]) * cst1 + sigm(acc[4]) * tanh_(acc[6]);
        cst1 = cn;
        hn1 = sigm(acc[7]) * tanh_(cn);
      }
      if (l < 2) {
        const ull pv = pack(l ? hn1 : hn0, (unsigned)(u + 1));
        ast(h1r + ((u & 3) << 9) + kg + l, pv);
        ast(y1r + ((u & 3) << 9) + kg + l, pv);
      }
    }
  } else {
    // ================= output projection =================
    const int b = bid - 64;
    float w[32], bs[4];
#pragma unroll
    for (int r = 0; r < 4; ++r) {
      const int row = (b << 5) + (wv << 2) + r;
      bs[r] = (row < 128) ? bp[row] : bv[row - 128];
#pragma unroll
      for (int j = 0; j < 8; ++j) {
        const int c = l + (j << 6);
        w[r * 8 + j] = (row < 128) ? Wp[(row << 9) + c] : Wv[((row - 128) << 9) + c];
      }
    }
    for (int u = 0; u < NT; ++u) {
      const ull* yp = y1r + ((u & 3) << 9);
      const unsigned ty = (unsigned)(u + 1);
      ull d[8];
      while (true) {
        bool ok = true;
#pragma unroll
        for (int j = 0; j < 8; ++j) { d[j] = ald(yp + (j << 6) + l); ok &= (thi(d[j]) == ty); }
        if (__all(ok)) break;
      }
      float a0 = 0.f, a1 = 0.f, a2 = 0.f, a3 = 0.f;
#pragma unroll
      for (int j = 0; j < 8; ++j) {
        const float hv = vlo(d[j]);
        a0 = fmaf(w[0 * 8 + j], hv, a0);
        a1 = fmaf(w[1 * 8 + j], hv, a1);
        a2 = fmaf(w[2 * 8 + j], hv, a2);
        a3 = fmaf(w[3 * 8 + j], hv, a3);
      }
#pragma unroll
      for (int off = 32; off > 0; off >>= 1) {
        a0 += __shfl_xor(a0, off, 64);
        a1 += __shfl_xor(a1, off, 64);
        a2 += __shfl_xor(a2, off, 64);
        a3 += __shfl_xor(a3, off, 64);
      }
      if (l < 4) {
        const int row = (b << 5) + (wv << 2) + l;
        const float val = (l == 0) ? a0 + bs[0]
                        : (l == 1) ? a1 + bs[1]
                        : (l == 2) ? a2 + bs[2]
                                   : a3 + bs[3];
        dout[(size_t)u * 256 + row] = val;
        ast(xr + (((u + 3) & 3) << 8) + row, pack(val, (unsigned)(u + 4)));
      }
    }
  }
}

extern "C" void kernel_launch(void* const* d_in, const int* in_sizes, int n_in,
                              void* d_out, int out_size, void* d_ws, size_t ws_size,
                              hipStream_t stream) {
  const int* tempo = (const int*)d_in[0];
  const int* keysig = (const int*)d_in[1];
  const int* lenp = (const int*)d_in[2];
  const float* emb = (const float*)d_in[3];
  const float* Wih0 = (const float*)d_in[4];
  const float* Whh0 = (const float*)d_in[5];
  const float* bih0 = (const float*)d_in[6];
  const float* bhh0 = (const float*)d_in[7];
  const float* Wih1 = (const float*)d_in[8];
  const float* Whh1 = (const float*)d_in[9];
  const float* bih1 = (const float*)d_in[10];
  const float* bhh1 = (const float*)d_in[11];
  const float* Wp = (const float*)d_in[12];
  const float* bp = (const float*)d_in[13];
  const float* Wv = (const float*)d_in[14];
  const float* bv = (const float*)d_in[15];
  ull* ws8 = (ull*)d_ws;
  float* out = (float*)d_out;

  mg_init<<<16, 256, 0, stream>>>(ws8, emb, tempo, keysig, lenp);
  mg_main<<<72, 512, 0, stream>>>(ws8, Wih0, Whh0, bih0, bhh0, Wih1, Whh1, bih1, bhh1,
                                  Wp, bp, Wv, bv, lenp, out);
}